// Round 1
// baseline (402.202 us; speedup 1.0000x reference)
//
#include <hip/hip_runtime.h>

// Problem constants (from setup_inputs): B=16, C_img=3, H=448, W=1024.
#define BB 16
#define HH 448
#define WW 1024
constexpr int HW    = HH * WW;          // 458752
constexpr int TOTAL = BB * HW;          // 7340032
constexpr int NBLK  = 7168;             // 7168*256*4 == TOTAL exactly
constexpr int NTHR  = 256;

__device__ __forceinline__ float flow_at(const float* __restrict__ mean,
                                         const float* __restrict__ lv,
                                         const float* __restrict__ eps,
                                         int idx) {
    return mean[idx] + __expf(0.5f * lv[idx]) * eps[idx];
}

__global__ __launch_bounds__(NTHR) void elbo_main(
    const float* __restrict__ mean, const float* __restrict__ lv,
    const float* __restrict__ img1, const float* __restrict__ img2,
    const float* __restrict__ target, const float* __restrict__ eps,
    float2* __restrict__ partials)
{
    const int tid  = blockIdx.x * blockDim.x + threadIdx.x;
    const int nthr = gridDim.x * blockDim.x;

    float se = 0.0f;   // elbo partial
    float sp = 0.0f;   // epe partial

    for (int p = tid; p < TOTAL; p += nthr) {
        const int b = p / HW;
        const int r = p - b * HW;          // y*W + x
        const int y = r >> 10;             // W = 1024
        const int x = r & (WW - 1);

        const int base = b * 2 * HW + r;   // channel-0 index into (B,2,H,W) arrays

        // flow sample at (y,x)
        const float m0 = mean[base],       m1 = mean[base + HW];
        const float l0 = lv[base],         l1 = lv[base + HW];
        const float e0 = eps[base],        e1 = eps[base + HW];
        const float u = m0 + __expf(0.5f * l0) * e0;
        const float v = m1 + __expf(0.5f * l1) * e1;

        // ---- smoothness term ----
        float dx2 = 0.0f, dy2 = 0.0f;
        if (x < WW - 1) {
            const float ur = flow_at(mean, lv, eps, base + 1);
            const float vr = flow_at(mean, lv, eps, base + HW + 1);
            const float a = ur - u, c = vr - v;
            dx2 = a * a + c * c;
        }
        if (y < HH - 1) {
            const float ud = flow_at(mean, lv, eps, base + WW);
            const float vd = flow_at(mean, lv, eps, base + HW + WW);
            const float a = ud - u, c = vd - v;
            dy2 = a * a + c * c;
        }
        const float smooth = sqrtf(dx2 + dy2 + 1e-5f);

        // ---- data term: bilinear warp of img2 ----
        const float xs = (float)x + u;
        const float ys = (float)y + v;
        const float x0f = floorf(xs), y0f = floorf(ys);
        const float wx = xs - x0f,    wy = ys - y0f;
        int x0 = (int)x0f; x0 = min(max(x0, 0), WW - 1);
        const int x1 = min(x0 + 1, WW - 1);
        int y0 = (int)y0f; y0 = min(max(y0, 0), HH - 1);
        const int y1 = min(y0 + 1, HH - 1);

        const int b3  = b * 3 * HW;
        const int i00 = y0 * WW + x0, i01 = y0 * WW + x1;
        const int i10 = y1 * WW + x0, i11 = y1 * WW + x1;

        float A = 0.0f;
        #pragma unroll
        for (int c = 0; c < 3; ++c) {
            const int o = b3 + c * HW;
            const float v00 = img2[o + i00];
            const float v01 = img2[o + i01];
            const float v10 = img2[o + i10];
            const float v11 = img2[o + i11];
            const float top = v00 + wx * (v01 - v00);
            const float bot = v10 + wx * (v11 - v10);
            const float w   = top + wy * (bot - top);
            const float d   = img1[o + r] - w;
            A += d * d;
        }
        const float data = sqrtf(A + 1e-5f);

        // ---- EPE ----
        const float t0 = target[base], t1 = target[base + HW];
        const float du = m0 - t0, dv = m1 - t1;
        const float epe = sqrtf(du * du + dv * dv);

        se += data + smooth - 0.5f * (l0 + l1);
        sp += epe;
    }

    // ---- block reduction: wave shuffle then LDS across 4 waves ----
    #pragma unroll
    for (int off = 32; off > 0; off >>= 1) {
        se += __shfl_down(se, off);
        sp += __shfl_down(sp, off);
    }
    __shared__ float s_e[NTHR / 64], s_p[NTHR / 64];
    const int lane = threadIdx.x & 63;
    const int wid  = threadIdx.x >> 6;
    if (lane == 0) { s_e[wid] = se; s_p[wid] = sp; }
    __syncthreads();
    if (threadIdx.x == 0) {
        float te = 0.0f, tp = 0.0f;
        #pragma unroll
        for (int i = 0; i < NTHR / 64; ++i) { te += s_e[i]; tp += s_p[i]; }
        partials[blockIdx.x] = make_float2(te, tp);
    }
}

__global__ __launch_bounds__(256) void elbo_final(
    const float2* __restrict__ partials, float* __restrict__ out)
{
    double se = 0.0, sp = 0.0;
    for (int i = threadIdx.x; i < NBLK; i += 256) {
        const float2 v = partials[i];
        se += (double)v.x;
        sp += (double)v.y;
    }
    #pragma unroll
    for (int off = 32; off > 0; off >>= 1) {
        se += __shfl_down(se, off);
        sp += __shfl_down(sp, off);
    }
    __shared__ double s_e[4], s_p[4];
    const int lane = threadIdx.x & 63;
    const int wid  = threadIdx.x >> 6;
    if (lane == 0) { s_e[wid] = se; s_p[wid] = sp; }
    __syncthreads();
    if (threadIdx.x == 0) {
        double te = 0.0, tp = 0.0;
        #pragma unroll
        for (int i = 0; i < 4; ++i) { te += s_e[i]; tp += s_p[i]; }
        out[0] = (float)(te / (double)BB);
        out[1] = (float)(tp / (double)TOTAL);
    }
}

extern "C" void kernel_launch(void* const* d_in, const int* in_sizes, int n_in,
                              void* d_out, int out_size, void* d_ws, size_t ws_size,
                              hipStream_t stream) {
    const float* mean   = (const float*)d_in[0];
    const float* logvar = (const float*)d_in[1];
    const float* img1   = (const float*)d_in[2];
    const float* img2   = (const float*)d_in[3];
    const float* target = (const float*)d_in[4];
    const float* eps    = (const float*)d_in[5];
    float* out = (float*)d_out;
    float2* partials = (float2*)d_ws;   // NBLK * 8 bytes = 57 KiB

    elbo_main<<<NBLK, NTHR, 0, stream>>>(mean, logvar, img1, img2, target, eps, partials);
    elbo_final<<<1, 256, 0, stream>>>(partials, out);
}